// Round 23
// baseline (993.115 us; speedup 1.0000x reference)
//
#include <hip/hip_runtime.h>

// ResidualVectorQuantizer — bit-exact vs harness np ref (VERIFIED R14, absmax 0):
//   rr/cc: pure sequential sum of rounded squares
//   dot (einsum SSE3): l_i = fl(m_i+m_{i+4}), dot = (l0+l1)+(l2+l3)
//   dist = fl(fl(rr+cc) - fl(2*dot)); argmin first-min strict <.
// R23: R22 b128 group loads kept; select machinery replaced by 4 residue-split
// accumulators (best value + wave-uniform group id -> SGPR-source cndmask, no
// index materialization). Reconstruct k=kb+4g+j per residue, ordered pairwise
// combine (value, then smaller k on ties), verified cross-half combine.
// Distance arithmetic identical; first-min semantics exactly preserved.

#define TOKENS   262144      // B*T
#define D        8
#define K        1024
#define Q        8
#define LOSS_OFF 2097152
#define CODES_OFF 2097153

#define BLK      256
#define GRID     (TOKENS / BLK)   // 1024 blocks; each block owns 256 tokens

// pure sequential sum of 8 (verified tree)
__device__ __forceinline__ float np_sum8_pureseq(const float* __restrict__ p) {
#pragma clang fp contract(off)
  float s = p[0];
  s = s + p[1]; s = s + p[2]; s = s + p[3]; s = s + p[4];
  s = s + p[5]; s = s + p[6]; s = s + p[7];
  return s;
}

// ---- prep: cc[q*K+k] = sum(c*c) pure-seq ----
__global__ __launch_bounds__(BLK) void rvq_prep(const float* __restrict__ cb,
                                                float* __restrict__ cc) {
#pragma clang fp contract(off)
  int i = blockIdx.x * BLK + threadIdx.x;   // [0, Q*K)
  const float* c = cb + i * D;
  float p[D];
#pragma unroll
  for (int d = 0; d < D; ++d) p[d] = c[d] * c[d];
  cc[i] = np_sum8_pureseq(p);
}

// verified einsum-SSE3 distance for one (token,k): m_d=fl(r_d*c_d),
// l_i=m_i+m_{i+4}, dot=(l0+l1)+(l2+l3), s=fl(fl(rr+cc)-fl(2*dot))
#define DIST1(RF, RR, CX, OUT)                                            \
  {                                                                       \
    float m0 = RF[0] * cd0.CX, m1 = RF[1] * cd1.CX, m2 = RF[2] * cd2.CX,  \
          m3 = RF[3] * cd3.CX, m4 = RF[4] * cd4.CX, m5 = RF[5] * cd5.CX,  \
          m6 = RF[6] * cd6.CX, m7 = RF[7] * cd7.CX;                       \
    float l0 = m0 + m4, l1 = m1 + m5, l2 = m2 + m6, l3 = m3 + m7;         \
    float dot = (l0 + l1) + (l2 + l3);                                    \
    OUT = (RR + cc4.CX) - 2.0f * dot;                                     \
  }

// ordered pairwise combine: prefer smaller value; on exact tie smaller k
#define COMB(VA, KA, VB, KB, VO, KO)                                      \
  {                                                                       \
    bool t = (VB < VA) || ((VB == VA) && (KB < KA));                      \
    VO = t ? VB : VA;                                                     \
    KO = t ? KB : KA;                                                     \
  }

// ---- main ----
__global__ __launch_bounds__(BLK) void rvq_main(const float* __restrict__ x,
                                                const float* __restrict__ cb,
                                                const float* __restrict__ cct,
                                                float* __restrict__ out,
                                                double* __restrict__ partials) {
#pragma clang fp contract(off)
  __shared__ float sCT[D][K];   // 32 KiB TRANSPOSED codebook: sCT[d][k]
  __shared__ float sCC[K];      // 4 KiB ||c||^2
  const int tid  = threadIdx.x;
  const int wid  = tid >> 6;
  const int lane = tid & 63;
  const int half = lane >> 5;         // 0: k in [0,512), 1: [512,1024)
  const int sub  = lane & 31;
  const int t0 = blockIdx.x * 256 + wid * 64 + sub;   // token A
  const int t1 = t0 + 32;                             // token B
  const int kb = half * (K / 2);

  float rfA[D], rfB[D], qvA[D], qvB[D];
  {
    const float4* xa = (const float4*)(x + t0 * D);
    const float4* xb = (const float4*)(x + t1 * D);
    float4 a0 = xa[0], a1 = xa[1], b0 = xb[0], b1 = xb[1];
    rfA[0] = a0.x; rfA[1] = a0.y; rfA[2] = a0.z; rfA[3] = a0.w;
    rfA[4] = a1.x; rfA[5] = a1.y; rfA[6] = a1.z; rfA[7] = a1.w;
    rfB[0] = b0.x; rfB[1] = b0.y; rfB[2] = b0.z; rfB[3] = b0.w;
    rfB[4] = b1.x; rfB[5] = b1.y; rfB[6] = b1.z; rfB[7] = b1.w;
#pragma unroll
    for (int d = 0; d < D; ++d) { qvA[d] = 0.0f; qvB[d] = 0.0f; }
  }
  double lossAcc = 0.0;

  for (int q = 0; q < Q; ++q) {
    __syncthreads();
    {
      const float* cbq = cb + q * (K * D);
      float* flat = (float*)sCT;
      for (int i = tid; i < K * D; i += BLK)
        flat[i] = cbq[(i & (K - 1)) * D + (i >> 10)];   // sCT[d][k] = cb[k][d]
      const float* ccq = cct + q * K;
      for (int i = tid; i < K; i += BLK) sCC[i] = ccq[i];
    }
    __syncthreads();

    // rr = pure-seq sum of rounded squares (verified tree)
    float rrA, rrB;
    {
      float p[D];
#pragma unroll
      for (int d = 0; d < D; ++d) p[d] = rfA[d] * rfA[d];
      rrA = np_sum8_pureseq(p);
#pragma unroll
      for (int d = 0; d < D; ++d) p[d] = rfB[d] * rfB[d];
      rrB = np_sum8_pureseq(p);
    }

    // half-scan: 128 groups of 4 k; residue-split accumulators (g uniform)
    const float INF = 3.402823466e+38f;
    float bvA0 = INF, bvA1 = INF, bvA2 = INF, bvA3 = INF;
    float bvB0 = INF, bvB1 = INF, bvB2 = INF, bvB3 = INF;
    int bgA0 = 0, bgA1 = 0, bgA2 = 0, bgA3 = 0;
    int bgB0 = 0, bgB1 = 0, bgB2 = 0, bgB3 = 0;
    const float* ccb = &sCC[kb];
    for (int g = 0; g < K / 8; ++g) {   // 128 groups per half
      const int k = kb + g * 4;
      float4 cd0 = *(const float4*)&sCT[0][k];
      float4 cd1 = *(const float4*)&sCT[1][k];
      float4 cd2 = *(const float4*)&sCT[2][k];
      float4 cd3 = *(const float4*)&sCT[3][k];
      float4 cd4 = *(const float4*)&sCT[4][k];
      float4 cd5 = *(const float4*)&sCT[5][k];
      float4 cd6 = *(const float4*)&sCT[6][k];
      float4 cd7 = *(const float4*)&sCT[7][k];
      float4 cc4 = *(const float4*)&ccb[g * 4];

      float sa0, sa1, sa2, sa3, sb0, sb1, sb2, sb3;
      DIST1(rfA, rrA, x, sa0)
      DIST1(rfA, rrA, y, sa1)
      DIST1(rfA, rrA, z, sa2)
      DIST1(rfA, rrA, w, sa3)
      if (sa0 < bvA0) { bvA0 = sa0; bgA0 = g; }
      if (sa1 < bvA1) { bvA1 = sa1; bgA1 = g; }
      if (sa2 < bvA2) { bvA2 = sa2; bgA2 = g; }
      if (sa3 < bvA3) { bvA3 = sa3; bgA3 = g; }

      DIST1(rfB, rrB, x, sb0)
      DIST1(rfB, rrB, y, sb1)
      DIST1(rfB, rrB, z, sb2)
      DIST1(rfB, rrB, w, sb3)
      if (sb0 < bvB0) { bvB0 = sb0; bgB0 = g; }
      if (sb1 < bvB1) { bvB1 = sb1; bgB1 = g; }
      if (sb2 < bvB2) { bvB2 = sb2; bgB2 = g; }
      if (sb3 < bvB3) { bvB3 = sb3; bgB3 = g; }
    }

    // reconstruct half-local winner (value, then smallest k on ties)
    float bestA, bestB;
    int ia, ib;
    {
      int k0 = kb + 4 * bgA0, k1 = kb + 4 * bgA1 + 1,
          k2 = kb + 4 * bgA2 + 2, k3 = kb + 4 * bgA3 + 3;
      float v01, v23; int i01, i23;
      COMB(bvA0, k0, bvA1, k1, v01, i01)
      COMB(bvA2, k2, bvA3, k3, v23, i23)
      COMB(v01, i01, v23, i23, bestA, ia)
    }
    {
      int k0 = kb + 4 * bgB0, k1 = kb + 4 * bgB1 + 1,
          k2 = kb + 4 * bgB2 + 2, k3 = kb + 4 * bgB3 + 3;
      float v01, v23; int i01, i23;
      COMB(bvB0, k0, bvB1, k1, v01, i01)
      COMB(bvB2, k2, bvB3, k3, v23, i23)
      COMB(v01, i01, v23, i23, bestB, ib)
    }

    // combine halves: lo wins ties (== numpy first-min over full K)
    float obA = __shfl_xor(bestA, 32);
    float obB = __shfl_xor(bestB, 32);
    int   oiA = __shfl_xor(ia, 32);
    int   oiB = __shfl_xor(ib, 32);
    float loA = half ? obA : bestA,  hiA = half ? bestA : obA;
    int   liA = half ? oiA : ia,     hiiA = half ? ia : oiA;
    int idxA = (loA <= hiA) ? liA : hiiA;
    float loB = half ? obB : bestB,  hiB = half ? bestB : obB;
    int   liB = half ? oiB : ib,     hiiB = half ? ib : oiB;
    int idxB = (loB <= hiB) ? liB : hiiB;

    // f32 update chain (gather from transposed layout; both halves in sync)
#pragma unroll
    for (int d = 0; d < D; ++d) {
      float eA = sCT[d][idxA];
      qvA[d] = qvA[d] + eA;
      rfA[d] = rfA[d] - eA;
      float fA = rfA[d] - eA;
      float eB = sCT[d][idxB];
      qvB[d] = qvB[d] + eB;
      rfB[d] = rfB[d] - eB;
      float fB = rfB[d] - eB;
      if (!half) {
        lossAcc = fma((double)fA, (double)fA, lossAcc);
        lossAcc = fma((double)fB, (double)fB, lossAcc);
      }
    }
    if (!half) {
      out[CODES_OFF + q * TOKENS + t0] = (float)idxA;
      out[CODES_OFF + q * TOKENS + t1] = (float)idxB;
    }
  }

  // straight-through: out_q = f32(x + f32(q - x)) — half 0 writes
  if (!half) {
    const float4* xa = (const float4*)(x + t0 * D);
    const float4* xb = (const float4*)(x + t1 * D);
    float4 a0 = xa[0], a1 = xa[1], b0 = xb[0], b1 = xb[1];
    float xsA[D] = {a0.x, a0.y, a0.z, a0.w, a1.x, a1.y, a1.z, a1.w};
    float xsB[D] = {b0.x, b0.y, b0.z, b0.w, b1.x, b1.y, b1.z, b1.w};
    float oA[D], oB[D];
#pragma unroll
    for (int d = 0; d < D; ++d) {
      oA[d] = xsA[d] + (qvA[d] - xsA[d]);
      oB[d] = xsB[d] + (qvB[d] - xsB[d]);
    }
    float4 v;
    v.x = oA[0]; v.y = oA[1]; v.z = oA[2]; v.w = oA[3];
    ((float4*)(out + t0 * D))[0] = v;
    v.x = oA[4]; v.y = oA[5]; v.z = oA[6]; v.w = oA[7];
    ((float4*)(out + t0 * D))[1] = v;
    v.x = oB[0]; v.y = oB[1]; v.z = oB[2]; v.w = oB[3];
    ((float4*)(out + t1 * D))[0] = v;
    v.x = oB[4]; v.y = oB[5]; v.z = oB[6]; v.w = oB[7];
    ((float4*)(out + t1 * D))[1] = v;
  }

  // block loss reduction (half-1 lanes contribute 0)
  for (int off = 32; off; off >>= 1) lossAcc += __shfl_down(lossAcc, off);
  __syncthreads();
  double* red = (double*)sCT;
  if ((tid & 63) == 0) red[tid >> 6] = lossAcc;
  __syncthreads();
  if (tid == 0) partials[blockIdx.x] = red[0] + red[1] + red[2] + red[3];
}

// ---- finalize loss (GRID=1024 partials) ----
__global__ __launch_bounds__(BLK) void rvq_loss(const double* __restrict__ partials,
                                                float* __restrict__ out) {
  int tid = threadIdx.x;
  double s = partials[tid] + partials[tid + BLK] +
             partials[tid + 2 * BLK] + partials[tid + 3 * BLK];
  for (int off = 32; off; off >>= 1) s += __shfl_down(s, off);
  __shared__ double red[4];
  if ((tid & 63) == 0) red[tid >> 6] = s;
  __syncthreads();
  if (tid == 0)
    out[LOSS_OFF] = (float)((red[0] + red[1] + red[2] + red[3]) *
                            (0.25 / 2097152.0));
}

extern "C" void kernel_launch(void* const* d_in, const int* in_sizes, int n_in,
                              void* d_out, int out_size, void* d_ws, size_t ws_size,
                              hipStream_t stream) {
  const float* x  = (const float*)d_in[0];
  const float* cb = (const float*)d_in[1];
  float* out = (float*)d_out;
  double* partials = (double*)d_ws;          // GRID doubles (8 KiB)
  float* cc = (float*)(partials + GRID);     // Q*K floats (32 KiB)

  rvq_prep<<<(Q * K) / BLK, BLK, 0, stream>>>(cb, cc);
  rvq_main<<<GRID, BLK, 0, stream>>>(x, cb, cc, out, partials);
  rvq_loss<<<1, BLK, 0, stream>>>(partials, out);
}

// Round 24
// 967.624 us; speedup vs baseline: 1.0263x; 1.0263x over previous
//
#include <hip/hip_runtime.h>

// ResidualVectorQuantizer — bit-exact vs harness np ref (VERIFIED R14, absmax 0):
//   rr/cc: pure sequential sum of rounded squares
//   dot (einsum SSE3): l_i = fl(m_i+m_{i+4}), dot = (l0+l1)+(l2+l3)
//   dist = fl(fl(rr+cc) - fl(2*dot)); argmin first-min strict <.
// R24: R20 skeleton, scalar math (no v2f), k-pair float2 LDS loads with
// unroll 4 (DS offset-immediate addressing), residue-2 accumulators with
// wave-uniform kp (SGPR cndmask source — no index materialization).
// Reconstruct + ordered tie-break (value, then smaller k) per stage;
// verified cross-half combine. Distance arithmetic identical.

#define TOKENS   262144      // B*T
#define D        8
#define K        1024
#define Q        8
#define LOSS_OFF 2097152
#define CODES_OFF 2097153

#define BLK      256
#define GRID     (TOKENS / BLK)   // 1024 blocks; each block owns 256 tokens

// pure sequential sum of 8 (verified tree)
__device__ __forceinline__ float np_sum8_pureseq(const float* __restrict__ p) {
#pragma clang fp contract(off)
  float s = p[0];
  s = s + p[1]; s = s + p[2]; s = s + p[3]; s = s + p[4];
  s = s + p[5]; s = s + p[6]; s = s + p[7];
  return s;
}

// ---- prep: cc[q*K+k] = sum(c*c) pure-seq ----
__global__ __launch_bounds__(BLK) void rvq_prep(const float* __restrict__ cb,
                                                float* __restrict__ cc) {
#pragma clang fp contract(off)
  int i = blockIdx.x * BLK + threadIdx.x;   // [0, Q*K)
  const float* c = cb + i * D;
  float p[D];
#pragma unroll
  for (int d = 0; d < D; ++d) p[d] = c[d] * c[d];
  cc[i] = np_sum8_pureseq(p);
}

// ---- main ----
__global__ __launch_bounds__(BLK) void rvq_main(const float* __restrict__ x,
                                                const float* __restrict__ cb,
                                                const float* __restrict__ cct,
                                                float* __restrict__ out,
                                                double* __restrict__ partials) {
#pragma clang fp contract(off)
  __shared__ float sCT[D][K];   // 32 KiB TRANSPOSED codebook: sCT[d][k]
  __shared__ float sCC[K];      // 4 KiB ||c||^2
  const int tid  = threadIdx.x;
  const int wid  = tid >> 6;
  const int lane = tid & 63;
  const int half = lane >> 5;         // 0: k in [0,512), 1: [512,1024)
  const int sub  = lane & 31;
  const int t0 = blockIdx.x * 256 + wid * 64 + sub;   // token A
  const int t1 = t0 + 32;                             // token B
  const int kb = half * (K / 2);

  float rfA[D], rfB[D], qvA[D], qvB[D];
  {
    const float4* xa = (const float4*)(x + t0 * D);
    const float4* xb = (const float4*)(x + t1 * D);
    float4 a0 = xa[0], a1 = xa[1], b0 = xb[0], b1 = xb[1];
    rfA[0] = a0.x; rfA[1] = a0.y; rfA[2] = a0.z; rfA[3] = a0.w;
    rfA[4] = a1.x; rfA[5] = a1.y; rfA[6] = a1.z; rfA[7] = a1.w;
    rfB[0] = b0.x; rfB[1] = b0.y; rfB[2] = b0.z; rfB[3] = b0.w;
    rfB[4] = b1.x; rfB[5] = b1.y; rfB[6] = b1.z; rfB[7] = b1.w;
#pragma unroll
    for (int d = 0; d < D; ++d) { qvA[d] = 0.0f; qvB[d] = 0.0f; }
  }
  double lossAcc = 0.0;

  for (int q = 0; q < Q; ++q) {
    __syncthreads();
    {
      const float* cbq = cb + q * (K * D);
      float* flat = (float*)sCT;
      for (int i = tid; i < K * D; i += BLK)
        flat[i] = cbq[(i & (K - 1)) * D + (i >> 10)];   // sCT[d][k] = cb[k][d]
      const float* ccq = cct + q * K;
      for (int i = tid; i < K; i += BLK) sCC[i] = ccq[i];
    }
    __syncthreads();

    // rr = pure-seq sum of rounded squares (verified tree)
    float rrA, rrB;
    {
      float p[D];
#pragma unroll
      for (int d = 0; d < D; ++d) p[d] = rfA[d] * rfA[d];
      rrA = np_sum8_pureseq(p);
#pragma unroll
      for (int d = 0; d < D; ++d) p[d] = rfB[d] * rfB[d];
      rrB = np_sum8_pureseq(p);
    }

    // half-scan: 256 k-pairs; residue-2 accumulators, kp wave-uniform
    const float INF = 3.402823466e+38f;
    float bvA0 = INF, bvA1 = INF, bvB0 = INF, bvB1 = INF;
    int bgA0 = 0, bgA1 = 0, bgB0 = 0, bgB1 = 0;
    const float* ccb = &sCC[kb];
#pragma unroll 4
    for (int kp = 0; kp < K / 4; ++kp) {   // 256 pair-iters per half
      const int k = kb + kp * 2;
      float2 cd0 = *(const float2*)&sCT[0][k];
      float2 cd1 = *(const float2*)&sCT[1][k];
      float2 cd2 = *(const float2*)&sCT[2][k];
      float2 cd3 = *(const float2*)&sCT[3][k];
      float2 cd4 = *(const float2*)&sCT[4][k];
      float2 cd5 = *(const float2*)&sCT[5][k];
      float2 cd6 = *(const float2*)&sCT[6][k];
      float2 cd7 = *(const float2*)&sCT[7][k];
      float2 ccp = *(const float2*)&ccb[kp * 2];

      // token A, even k (.x)
      {
        float m0 = rfA[0] * cd0.x, m1 = rfA[1] * cd1.x, m2 = rfA[2] * cd2.x,
              m3 = rfA[3] * cd3.x, m4 = rfA[4] * cd4.x, m5 = rfA[5] * cd5.x,
              m6 = rfA[6] * cd6.x, m7 = rfA[7] * cd7.x;
        float l0 = m0 + m4, l1 = m1 + m5, l2 = m2 + m6, l3 = m3 + m7;
        float dot = (l0 + l1) + (l2 + l3);
        float s = (rrA + ccp.x) - 2.0f * dot;
        if (s < bvA0) { bvA0 = s; bgA0 = kp; }
      }
      // token A, odd k (.y)
      {
        float m0 = rfA[0] * cd0.y, m1 = rfA[1] * cd1.y, m2 = rfA[2] * cd2.y,
              m3 = rfA[3] * cd3.y, m4 = rfA[4] * cd4.y, m5 = rfA[5] * cd5.y,
              m6 = rfA[6] * cd6.y, m7 = rfA[7] * cd7.y;
        float l0 = m0 + m4, l1 = m1 + m5, l2 = m2 + m6, l3 = m3 + m7;
        float dot = (l0 + l1) + (l2 + l3);
        float s = (rrA + ccp.y) - 2.0f * dot;
        if (s < bvA1) { bvA1 = s; bgA1 = kp; }
      }
      // token B, even k (.x)
      {
        float m0 = rfB[0] * cd0.x, m1 = rfB[1] * cd1.x, m2 = rfB[2] * cd2.x,
              m3 = rfB[3] * cd3.x, m4 = rfB[4] * cd4.x, m5 = rfB[5] * cd5.x,
              m6 = rfB[6] * cd6.x, m7 = rfB[7] * cd7.x;
        float l0 = m0 + m4, l1 = m1 + m5, l2 = m2 + m6, l3 = m3 + m7;
        float dot = (l0 + l1) + (l2 + l3);
        float s = (rrB + ccp.x) - 2.0f * dot;
        if (s < bvB0) { bvB0 = s; bgB0 = kp; }
      }
      // token B, odd k (.y)
      {
        float m0 = rfB[0] * cd0.y, m1 = rfB[1] * cd1.y, m2 = rfB[2] * cd2.y,
              m3 = rfB[3] * cd3.y, m4 = rfB[4] * cd4.y, m5 = rfB[5] * cd5.y,
              m6 = rfB[6] * cd6.y, m7 = rfB[7] * cd7.y;
        float l0 = m0 + m4, l1 = m1 + m5, l2 = m2 + m6, l3 = m3 + m7;
        float dot = (l0 + l1) + (l2 + l3);
        float s = (rrB + ccp.y) - 2.0f * dot;
        if (s < bvB1) { bvB1 = s; bgB1 = kp; }
      }
    }

    // reconstruct half winner: value first, smaller k on exact tie
    float bestA, bestB;
    int ia, ib;
    {
      int k0 = kb + 2 * bgA0, k1 = kb + 2 * bgA1 + 1;
      bool t = (bvA1 < bvA0) || ((bvA1 == bvA0) && (k1 < k0));
      bestA = t ? bvA1 : bvA0;
      ia = t ? k1 : k0;
    }
    {
      int k0 = kb + 2 * bgB0, k1 = kb + 2 * bgB1 + 1;
      bool t = (bvB1 < bvB0) || ((bvB1 == bvB0) && (k1 < k0));
      bestB = t ? bvB1 : bvB0;
      ib = t ? k1 : k0;
    }

    // combine halves: lo wins ties (== numpy first-min over full K)
    float obA = __shfl_xor(bestA, 32);
    float obB = __shfl_xor(bestB, 32);
    int   oiA = __shfl_xor(ia, 32);
    int   oiB = __shfl_xor(ib, 32);
    float loA = half ? obA : bestA,  hiA = half ? bestA : obA;
    int   liA = half ? oiA : ia,     hiiA = half ? ia : oiA;
    int idxA = (loA <= hiA) ? liA : hiiA;
    float loB = half ? obB : bestB,  hiB = half ? bestB : obB;
    int   liB = half ? oiB : ib,     hiiB = half ? ib : oiB;
    int idxB = (loB <= hiB) ? liB : hiiB;

    // f32 update chain (gather from transposed layout; both halves in sync)
#pragma unroll
    for (int d = 0; d < D; ++d) {
      float eA = sCT[d][idxA];
      qvA[d] = qvA[d] + eA;
      rfA[d] = rfA[d] - eA;
      float fA = rfA[d] - eA;
      float eB = sCT[d][idxB];
      qvB[d] = qvB[d] + eB;
      rfB[d] = rfB[d] - eB;
      float fB = rfB[d] - eB;
      if (!half) {
        lossAcc = fma((double)fA, (double)fA, lossAcc);
        lossAcc = fma((double)fB, (double)fB, lossAcc);
      }
    }
    if (!half) {
      out[CODES_OFF + q * TOKENS + t0] = (float)idxA;
      out[CODES_OFF + q * TOKENS + t1] = (float)idxB;
    }
  }

  // straight-through: out_q = f32(x + f32(q - x)) — half 0 writes
  if (!half) {
    const float4* xa = (const float4*)(x + t0 * D);
    const float4* xb = (const float4*)(x + t1 * D);
    float4 a0 = xa[0], a1 = xa[1], b0 = xb[0], b1 = xb[1];
    float xsA[D] = {a0.x, a0.y, a0.z, a0.w, a1.x, a1.y, a1.z, a1.w};
    float xsB[D] = {b0.x, b0.y, b0.z, b0.w, b1.x, b1.y, b1.z, b1.w};
    float oA[D], oB[D];
#pragma unroll
    for (int d = 0; d < D; ++d) {
      oA[d] = xsA[d] + (qvA[d] - xsA[d]);
      oB[d] = xsB[d] + (qvB[d] - xsB[d]);
    }
    float4 v;
    v.x = oA[0]; v.y = oA[1]; v.z = oA[2]; v.w = oA[3];
    ((float4*)(out + t0 * D))[0] = v;
    v.x = oA[4]; v.y = oA[5]; v.z = oA[6]; v.w = oA[7];
    ((float4*)(out + t0 * D))[1] = v;
    v.x = oB[0]; v.y = oB[1]; v.z = oB[2]; v.w = oB[3];
    ((float4*)(out + t1 * D))[0] = v;
    v.x = oB[4]; v.y = oB[5]; v.z = oB[6]; v.w = oB[7];
    ((float4*)(out + t1 * D))[1] = v;
  }

  // block loss reduction (half-1 lanes contribute 0)
  for (int off = 32; off; off >>= 1) lossAcc += __shfl_down(lossAcc, off);
  __syncthreads();
  double* red = (double*)sCT;
  if ((tid & 63) == 0) red[tid >> 6] = lossAcc;
  __syncthreads();
  if (tid == 0) partials[blockIdx.x] = red[0] + red[1] + red[2] + red[3];
}

// ---- finalize loss (GRID=1024 partials) ----
__global__ __launch_bounds__(BLK) void rvq_loss(const double* __restrict__ partials,
                                                float* __restrict__ out) {
  int tid = threadIdx.x;
  double s = partials[tid] + partials[tid + BLK] +
             partials[tid + 2 * BLK] + partials[tid + 3 * BLK];
  for (int off = 32; off; off >>= 1) s += __shfl_down(s, off);
  __shared__ double red[4];
  if ((tid & 63) == 0) red[tid >> 6] = s;
  __syncthreads();
  if (tid == 0)
    out[LOSS_OFF] = (float)((red[0] + red[1] + red[2] + red[3]) *
                            (0.25 / 2097152.0));
}

extern "C" void kernel_launch(void* const* d_in, const int* in_sizes, int n_in,
                              void* d_out, int out_size, void* d_ws, size_t ws_size,
                              hipStream_t stream) {
  const float* x  = (const float*)d_in[0];
  const float* cb = (const float*)d_in[1];
  float* out = (float*)d_out;
  double* partials = (double*)d_ws;          // GRID doubles (8 KiB)
  float* cc = (float*)(partials + GRID);     // Q*K floats (32 KiB)

  rvq_prep<<<(Q * K) / BLK, BLK, 0, stream>>>(cb, cc);
  rvq_main<<<GRID, BLK, 0, stream>>>(x, cb, cc, out, partials);
  rvq_loss<<<1, BLK, 0, stream>>>(partials, out);
}

// Round 25
// 884.133 us; speedup vs baseline: 1.1233x; 1.0944x over previous
//
#include <hip/hip_runtime.h>

// ResidualVectorQuantizer — bit-exact vs harness np ref (VERIFIED R14, absmax 0):
//   rr/cc: pure sequential sum of rounded squares
//   dot (einsum SSE3): l_i = fl(m_i+m_{i+4}), dot = (l0+l1)+(l2+l3)
//   dist = fl(fl(rr+cc) - fl(2*dot)); argmin first-min strict <.
// R25 = R20 verbatim (best measured: 886 µs bench). The R21-R24 trim campaign
// (pk-f32 asm, b128 groups, residue accumulators, unroll variants) all
// regressed or were null; reverting to best-known before declaring ceiling.

#define TOKENS   262144      // B*T
#define D        8
#define K        1024
#define Q        8
#define LOSS_OFF 2097152
#define CODES_OFF 2097153

#define BLK      256
#define GRID     (TOKENS / BLK)   // 1024 blocks; each block owns 256 tokens

typedef float v2f __attribute__((ext_vector_type(2)));

// pure sequential sum of 8 (verified tree)
__device__ __forceinline__ float np_sum8_pureseq(const float* __restrict__ p) {
#pragma clang fp contract(off)
  float s = p[0];
  s = s + p[1]; s = s + p[2]; s = s + p[3]; s = s + p[4];
  s = s + p[5]; s = s + p[6]; s = s + p[7];
  return s;
}

// ---- prep: cc[q*K+k] = sum(c*c) pure-seq ----
__global__ __launch_bounds__(BLK) void rvq_prep(const float* __restrict__ cb,
                                                float* __restrict__ cc) {
#pragma clang fp contract(off)
  int i = blockIdx.x * BLK + threadIdx.x;   // [0, Q*K)
  const float* c = cb + i * D;
  float p[D];
#pragma unroll
  for (int d = 0; d < D; ++d) p[d] = c[d] * c[d];
  cc[i] = np_sum8_pureseq(p);
}

// ---- main: lane pair (l, l+32) shares 2 tokens; halves split K; k-pair ----
__global__ __launch_bounds__(BLK) void rvq_main(const float* __restrict__ x,
                                                const float* __restrict__ cb,
                                                const float* __restrict__ cct,
                                                float* __restrict__ out,
                                                double* __restrict__ partials) {
#pragma clang fp contract(off)
  __shared__ float sCT[D][K];   // 32 KiB TRANSPOSED codebook: sCT[d][k]
  __shared__ float sCC[K];      // 4 KiB ||c||^2
  const int tid  = threadIdx.x;
  const int wid  = tid >> 6;
  const int lane = tid & 63;
  const int half = lane >> 5;         // 0: k in [0,512), 1: [512,1024)
  const int sub  = lane & 31;
  const int t0 = blockIdx.x * 256 + wid * 64 + sub;   // token A
  const int t1 = t0 + 32;                             // token B
  const int kb = half * (K / 2);

  float rfA[D], rfB[D], qvA[D], qvB[D];
  {
    const float4* xa = (const float4*)(x + t0 * D);
    const float4* xb = (const float4*)(x + t1 * D);
    float4 a0 = xa[0], a1 = xa[1], b0 = xb[0], b1 = xb[1];
    rfA[0] = a0.x; rfA[1] = a0.y; rfA[2] = a0.z; rfA[3] = a0.w;
    rfA[4] = a1.x; rfA[5] = a1.y; rfA[6] = a1.z; rfA[7] = a1.w;
    rfB[0] = b0.x; rfB[1] = b0.y; rfB[2] = b0.z; rfB[3] = b0.w;
    rfB[4] = b1.x; rfB[5] = b1.y; rfB[6] = b1.z; rfB[7] = b1.w;
#pragma unroll
    for (int d = 0; d < D; ++d) { qvA[d] = 0.0f; qvB[d] = 0.0f; }
  }
  double lossAcc = 0.0;

  for (int q = 0; q < Q; ++q) {
    __syncthreads();
    {
      const float* cbq = cb + q * (K * D);
      float* flat = (float*)sCT;
      for (int i = tid; i < K * D; i += BLK)
        flat[i] = cbq[(i & (K - 1)) * D + (i >> 10)];   // sCT[d][k] = cb[k][d]
      const float* ccq = cct + q * K;
      for (int i = tid; i < K; i += BLK) sCC[i] = ccq[i];
    }
    __syncthreads();

    // rr = pure-seq sum of rounded squares (verified tree)
    float rrA, rrB;
    {
      float p[D];
#pragma unroll
      for (int d = 0; d < D; ++d) p[d] = rfA[d] * rfA[d];
      rrA = np_sum8_pureseq(p);
#pragma unroll
      for (int d = 0; d < D; ++d) p[d] = rfB[d] * rfB[d];
      rrB = np_sum8_pureseq(p);
    }
    v2f rrA2 = (v2f){rrA, rrA}, rrB2 = (v2f){rrB, rrB};
    v2f rf2A[D], rf2B[D];
#pragma unroll
    for (int d = 0; d < D; ++d) {
      rf2A[d] = (v2f){rfA[d], rfA[d]};
      rf2B[d] = (v2f){rfB[d], rfB[d]};
    }

    // half-scan in k-pairs: components = {k, k+1}, verified tree per comp
    float bestA = 3.402823466e+38f, bestB = 3.402823466e+38f;
    int ia = kb, ib = kb;
    const float* ccb = &sCC[kb];
#pragma unroll 2
    for (int kp = 0; kp < K / 4; ++kp) {   // 256 pair-iters over this half
      const int k = kb + kp * 2;
      v2f cd[D];
#pragma unroll
      for (int d = 0; d < D; ++d)
        cd[d] = *(const v2f*)&sCT[d][k];       // ds_read_b64
      v2f cc2 = *(const v2f*)&ccb[kp * 2];

      // token A
      v2f a0 = rf2A[0] * cd[0], a1 = rf2A[1] * cd[1],
          a2 = rf2A[2] * cd[2], a3 = rf2A[3] * cd[3],
          a4 = rf2A[4] * cd[4], a5 = rf2A[5] * cd[5],
          a6 = rf2A[6] * cd[6], a7 = rf2A[7] * cd[7];
      v2f La0 = a0 + a4, La1 = a1 + a5, La2 = a2 + a6, La3 = a3 + a7;
      v2f dA = (La0 + La1) + (La2 + La3);
      v2f sA = (rrA2 + cc2) - (dA + dA);
      if (sA.x < bestA) { bestA = sA.x; ia = k; }
      if (sA.y < bestA) { bestA = sA.y; ia = k + 1; }

      // token B
      v2f b0 = rf2B[0] * cd[0], b1 = rf2B[1] * cd[1],
          b2 = rf2B[2] * cd[2], b3 = rf2B[3] * cd[3],
          b4 = rf2B[4] * cd[4], b5 = rf2B[5] * cd[5],
          b6 = rf2B[6] * cd[6], b7 = rf2B[7] * cd[7];
      v2f Lb0 = b0 + b4, Lb1 = b1 + b5, Lb2 = b2 + b6, Lb3 = b3 + b7;
      v2f dB = (Lb0 + Lb1) + (Lb2 + Lb3);
      v2f sB = (rrB2 + cc2) - (dB + dB);
      if (sB.x < bestB) { bestB = sB.x; ib = k; }
      if (sB.y < bestB) { bestB = sB.y; ib = k + 1; }
    }

    // combine halves: lo wins ties (== numpy first-min over full K)
    float obA = __shfl_xor(bestA, 32);
    float obB = __shfl_xor(bestB, 32);
    int   oiA = __shfl_xor(ia, 32);
    int   oiB = __shfl_xor(ib, 32);
    float loA = half ? obA : bestA,  hiA = half ? bestA : obA;
    int   liA = half ? oiA : ia,     hiiA = half ? ia : oiA;
    int idxA = (loA <= hiA) ? liA : hiiA;
    float loB = half ? obB : bestB,  hiB = half ? bestB : obB;
    int   liB = half ? oiB : ib,     hiiB = half ? ib : oiB;
    int idxB = (loB <= hiB) ? liB : hiiB;

    // f32 update chain (gather from transposed layout; both halves in sync)
#pragma unroll
    for (int d = 0; d < D; ++d) {
      float eA = sCT[d][idxA];
      qvA[d] = qvA[d] + eA;
      rfA[d] = rfA[d] - eA;
      float fA = rfA[d] - eA;
      float eB = sCT[d][idxB];
      qvB[d] = qvB[d] + eB;
      rfB[d] = rfB[d] - eB;
      float fB = rfB[d] - eB;
      if (!half) {
        lossAcc = fma((double)fA, (double)fA, lossAcc);
        lossAcc = fma((double)fB, (double)fB, lossAcc);
      }
    }
    if (!half) {
      out[CODES_OFF + q * TOKENS + t0] = (float)idxA;
      out[CODES_OFF + q * TOKENS + t1] = (float)idxB;
    }
  }

  // straight-through: out_q = f32(x + f32(q - x)) — half 0 writes
  if (!half) {
    const float4* xa = (const float4*)(x + t0 * D);
    const float4* xb = (const float4*)(x + t1 * D);
    float4 a0 = xa[0], a1 = xa[1], b0 = xb[0], b1 = xb[1];
    float xsA[D] = {a0.x, a0.y, a0.z, a0.w, a1.x, a1.y, a1.z, a1.w};
    float xsB[D] = {b0.x, b0.y, b0.z, b0.w, b1.x, b1.y, b1.z, b1.w};
    float oA[D], oB[D];
#pragma unroll
    for (int d = 0; d < D; ++d) {
      oA[d] = xsA[d] + (qvA[d] - xsA[d]);
      oB[d] = xsB[d] + (qvB[d] - xsB[d]);
    }
    float4 v;
    v.x = oA[0]; v.y = oA[1]; v.z = oA[2]; v.w = oA[3];
    ((float4*)(out + t0 * D))[0] = v;
    v.x = oA[4]; v.y = oA[5]; v.z = oA[6]; v.w = oA[7];
    ((float4*)(out + t0 * D))[1] = v;
    v.x = oB[0]; v.y = oB[1]; v.z = oB[2]; v.w = oB[3];
    ((float4*)(out + t1 * D))[0] = v;
    v.x = oB[4]; v.y = oB[5]; v.z = oB[6]; v.w = oB[7];
    ((float4*)(out + t1 * D))[1] = v;
  }

  // block loss reduction (half-1 lanes contribute 0)
  for (int off = 32; off; off >>= 1) lossAcc += __shfl_down(lossAcc, off);
  __syncthreads();
  double* red = (double*)sCT;
  if ((tid & 63) == 0) red[tid >> 6] = lossAcc;
  __syncthreads();
  if (tid == 0) partials[blockIdx.x] = red[0] + red[1] + red[2] + red[3];
}

// ---- finalize loss (GRID=1024 partials) ----
__global__ __launch_bounds__(BLK) void rvq_loss(const double* __restrict__ partials,
                                                float* __restrict__ out) {
  int tid = threadIdx.x;
  double s = partials[tid] + partials[tid + BLK] +
             partials[tid + 2 * BLK] + partials[tid + 3 * BLK];
  for (int off = 32; off; off >>= 1) s += __shfl_down(s, off);
  __shared__ double red[4];
  if ((tid & 63) == 0) red[tid >> 6] = s;
  __syncthreads();
  if (tid == 0)
    out[LOSS_OFF] = (float)((red[0] + red[1] + red[2] + red[3]) *
                            (0.25 / 2097152.0));
}

extern "C" void kernel_launch(void* const* d_in, const int* in_sizes, int n_in,
                              void* d_out, int out_size, void* d_ws, size_t ws_size,
                              hipStream_t stream) {
  const float* x  = (const float*)d_in[0];
  const float* cb = (const float*)d_in[1];
  float* out = (float*)d_out;
  double* partials = (double*)d_ws;          // GRID doubles (8 KiB)
  float* cc = (float*)(partials + GRID);     // Q*K floats (32 KiB)

  rvq_prep<<<(Q * K) / BLK, BLK, 0, stream>>>(cb, cc);
  rvq_main<<<GRID, BLK, 0, stream>>>(x, cb, cc, out, partials);
  rvq_loss<<<1, BLK, 0, stream>>>(partials, out);
}